// Round 2
// baseline (1188.370 us; speedup 1.0000x reference)
//
#include <hip/hip_runtime.h>
#include <hip/hip_fp16.h>

#define L_SEQ  1024
#define NBATCH 2048
#define NSTATE 64

typedef _Float16 half8  __attribute__((ext_vector_type(8)));
typedef _Float16 half2s __attribute__((ext_vector_type(2)));
typedef float    float4v __attribute__((ext_vector_type(4)));
typedef unsigned int uint2v __attribute__((ext_vector_type(2)));
typedef unsigned int uint4v __attribute__((ext_vector_type(4)));

// Split A_stacked (f32) into fp16 hi + lo so that hi+lo ~ 22-bit mantissa.
__global__ __launch_bounds__(256) void split_A_kernel(const float* __restrict__ A,
                                                      _Float16* __restrict__ hi,
                                                      _Float16* __restrict__ lo) {
    int i = blockIdx.x * 256 + threadIdx.x;
    float a = A[i];
    _Float16 h = (_Float16)a;
    hi[i] = h;
    lo[i] = (_Float16)(a - (float)h);
}

__device__ inline unsigned int pack_pair(float x, float y) {
    half2s h; h.x = (_Float16)x; h.y = (_Float16)y;
    return __builtin_bit_cast(unsigned int, h);
}

// One wave (64 lanes) per block; block owns 16 batch columns for the whole scan.
// Per step: D(16i x 16b per tile, 4 tiles) = A_t(hi/lo fp16) x c^T(hi/lo fp16), fp32 acc.
// c lives in XOR-swizzled, double-buffered LDS as packed fp16 pairs.
template <bool USE_WS>
__global__ __launch_bounds__(64, 1) void hippo_scan_kernel(
    const float* __restrict__ inp,      // (L, NBATCH)
    const float* __restrict__ bst,      // (L, NSTATE)
    const float* __restrict__ A32,      // (L, 64, 64)  — fallback path
    const _Float16* __restrict__ Ahi,   // (L, 64, 64)
    const _Float16* __restrict__ Alo,   // (L, 64, 64)
    float* __restrict__ out)            // (L, NBATCH, NSTATE)
{
    const int lane = threadIdx.x;   // 0..63
    const int col  = lane & 15;     // A-frag: row i (mod 16); B/D-frag: batch column
    const int quad = lane >> 4;     // 0..3
    const int b0   = blockIdx.x * 16;
    const int swz  = (col & 7) << 2;

    __shared__ unsigned int c_hi[1024];   // 2 buffers x 16 rows x 32 packed u32
    __shared__ unsigned int c_lo[1024];
    for (int i = lane; i < 1024; i += 64) { c_hi[i] = 0u; c_lo[i] = 0u; }
    __syncthreads();

    // B-frag read offsets (uint4 per kk): logical u32 idx = 16*kk + 4*quad, XOR-swizzled by row
    const int rd0 = col * 32 + (( 0 + 4 * quad) ^ swz);
    const int rd1 = col * 32 + ((16 + 4 * quad) ^ swz);
    // c-write offsets per i-tile: logical u32 idx = 8*tile + 2*quad, XOR-swizzled by row
    int wr[4];
#pragma unroll
    for (int ts = 0; ts < 4; ++ts) wr[ts] = col * 32 + ((8 * ts + 2 * quad) ^ swz);

    // A-frag element offsets within one (64x64) matrix
    int aoff[4][2];
#pragma unroll
    for (int tl = 0; tl < 4; ++tl)
#pragma unroll
        for (int kk = 0; kk < 2; ++kk)
            aoff[tl][kk] = (16 * tl + col) * 64 + 32 * kk + 8 * quad;

    half8 ah[4][2], al[4][2];
    float inpv;
    float4v bstv[4];

    auto load_step = [&](int t) {
#pragma unroll
        for (int tl = 0; tl < 4; ++tl) {
#pragma unroll
            for (int kk = 0; kk < 2; ++kk) {
                if constexpr (USE_WS) {
                    ah[tl][kk] = *(const half8*)(Ahi + (size_t)t * 4096 + aoff[tl][kk]);
                    al[tl][kk] = *(const half8*)(Alo + (size_t)t * 4096 + aoff[tl][kk]);
                } else {
                    const float* p = A32 + (size_t)t * 4096 + aoff[tl][kk];
                    float4v f0 = *(const float4v*)(p);
                    float4v f1 = *(const float4v*)(p + 4);
                    half8 h, l;
#pragma unroll
                    for (int e = 0; e < 4; ++e) {
                        float v0 = f0[e], v1 = f1[e];
                        _Float16 h0 = (_Float16)v0, h1 = (_Float16)v1;
                        h[e]     = h0;
                        h[e + 4] = h1;
                        l[e]     = (_Float16)(v0 - (float)h0);
                        l[e + 4] = (_Float16)(v1 - (float)h1);
                    }
                    ah[tl][kk] = h;
                    al[tl][kk] = l;
                }
            }
        }
        inpv = inp[t * NBATCH + b0 + col];
#pragma unroll
        for (int tl = 0; tl < 4; ++tl)
            bstv[tl] = *(const float4v*)(bst + t * NSTATE + 16 * tl + 4 * quad);
    };

    load_step(0);

    for (int t = 0; t < L_SEQ; ++t) {
        const int cur = (t & 1) << 9;
        const int nxt = cur ^ 512;

        // B-operand: c^T, packed fp16 pairs -> half8 frags
        uint4v u_h0 = *(const uint4v*)(c_hi + cur + rd0);
        uint4v u_h1 = *(const uint4v*)(c_hi + cur + rd1);
        uint4v u_l0 = *(const uint4v*)(c_lo + cur + rd0);
        uint4v u_l1 = *(const uint4v*)(c_lo + cur + rd1);
        half8 ch[2] = { __builtin_bit_cast(half8, u_h0), __builtin_bit_cast(half8, u_h1) };
        half8 cl[2] = { __builtin_bit_cast(half8, u_l0), __builtin_bit_cast(half8, u_l1) };

        // acc init with u_t = f_t * B_t  (exact f32)
        float4v acc[4];
#pragma unroll
        for (int tl = 0; tl < 4; ++tl) acc[tl] = bstv[tl] * inpv;

        // 3-term split-precision product, fp32 accumulate
#pragma unroll
        for (int tl = 0; tl < 4; ++tl) {
#pragma unroll
            for (int kk = 0; kk < 2; ++kk) {
                acc[tl] = __builtin_amdgcn_mfma_f32_16x16x32_f16(ah[tl][kk], ch[kk], acc[tl], 0, 0, 0);
                acc[tl] = __builtin_amdgcn_mfma_f32_16x16x32_f16(ah[tl][kk], cl[kk], acc[tl], 0, 0, 0);
                acc[tl] = __builtin_amdgcn_mfma_f32_16x16x32_f16(al[tl][kk], ch[kk], acc[tl], 0, 0, 0);
            }
        }

        // write c_t to global: lane has 4 consecutive i for its batch column
        float4v* outv = (float4v*)out;
#pragma unroll
        for (int tl = 0; tl < 4; ++tl)
            outv[(size_t)(t * NBATCH + b0 + col) * 16 + 4 * tl + quad] = acc[tl];

        // prefetch next step's A/inp/bst (A-frag regs are dead after the MFMAs)
        load_step(t + 1 < L_SEQ ? t + 1 : t);

        // split c into fp16 hi/lo, pack pairs, write to the other LDS buffer
#pragma unroll
        for (int tl = 0; tl < 4; ++tl) {
            float x = acc[tl].x, y = acc[tl].y, z = acc[tl].z, w = acc[tl].w;
            _Float16 hx = (_Float16)x, hy = (_Float16)y, hz = (_Float16)z, hw = (_Float16)w;
            half2s hp01; hp01.x = hx; hp01.y = hy;
            half2s hp23; hp23.x = hz; hp23.y = hw;
            half2s lp01; lp01.x = (_Float16)(x - (float)hx); lp01.y = (_Float16)(y - (float)hy);
            half2s lp23; lp23.x = (_Float16)(z - (float)hz); lp23.y = (_Float16)(w - (float)hw);
            uint2v hp = { __builtin_bit_cast(unsigned int, hp01), __builtin_bit_cast(unsigned int, hp23) };
            uint2v lp = { __builtin_bit_cast(unsigned int, lp01), __builtin_bit_cast(unsigned int, lp23) };
            *(uint2v*)(c_hi + nxt + wr[tl]) = hp;
            *(uint2v*)(c_lo + nxt + wr[tl]) = lp;
        }
        __syncthreads();
    }
}

extern "C" void kernel_launch(void* const* d_in, const int* in_sizes, int n_in,
                              void* d_out, int out_size, void* d_ws, size_t ws_size,
                              hipStream_t stream) {
    const float* inputs = (const float*)d_in[0];
    const float* A_st   = (const float*)d_in[1];
    const float* B_st   = (const float*)d_in[2];
    float* out = (float*)d_out;

    const size_t n_a  = (size_t)L_SEQ * NSTATE * NSTATE;     // 4,194,304
    const size_t need = n_a * 2 * sizeof(_Float16);          // 16 MiB

    if (ws_size >= need) {
        _Float16* Ahi = (_Float16*)d_ws;
        _Float16* Alo = Ahi + n_a;
        split_A_kernel<<<(int)(n_a / 256), 256, 0, stream>>>(A_st, Ahi, Alo);
        hippo_scan_kernel<true><<<NBATCH / 16, 64, 0, stream>>>(inputs, B_st, A_st, Ahi, Alo, out);
    } else {
        hippo_scan_kernel<false><<<NBATCH / 16, 64, 0, stream>>>(inputs, B_st, A_st, nullptr, nullptr, out);
    }
}

// Round 3
// 1010.226 us; speedup vs baseline: 1.1763x; 1.1763x over previous
//
#include <hip/hip_runtime.h>
#include <hip/hip_fp16.h>

#define L_SEQ  1024
#define NBATCH 2048
#define NSTATE 64

typedef _Float16 half8  __attribute__((ext_vector_type(8)));
typedef __fp16   fp16v2 __attribute__((ext_vector_type(2)));
typedef float    float4v __attribute__((ext_vector_type(4)));
typedef unsigned int uint2v __attribute__((ext_vector_type(2)));
typedef unsigned int uint4v __attribute__((ext_vector_type(4)));

// Split A_stacked (f32) into fp16 hi + lo so that hi+lo ~ 22-bit mantissa.
__global__ __launch_bounds__(256) void split_A_kernel(const float* __restrict__ A,
                                                      _Float16* __restrict__ hi,
                                                      _Float16* __restrict__ lo) {
    int i = blockIdx.x * 256 + threadIdx.x;
    float a = A[i];
    _Float16 h = (_Float16)a;
    hi[i] = h;
    lo[i] = (_Float16)(a - (float)h);
}

// One wave (64 lanes) per block; block owns 16 batch columns for the whole scan.
// Single-wave block => NO __syncthreads needed: DS ops from one wave execute in
// program order, so the LDS write->read of c is ordered by hardware; removing the
// barrier removes the s_waitcnt vmcnt(0) drain that exposed A-load latency.
// A/inp/bst prefetched 2 steps ahead into two NAMED register sets (no runtime
// indexing -> stays in VGPRs).
template <bool USE_WS>
__global__ __launch_bounds__(64, 1) void hippo_scan_kernel(
    const float* __restrict__ inp,      // (L, NBATCH)
    const float* __restrict__ bst,      // (L, NSTATE)
    const float* __restrict__ A32,      // (L, 64, 64)  — fallback path
    const _Float16* __restrict__ Ahi,   // (L, 64, 64)
    const _Float16* __restrict__ Alo,   // (L, 64, 64)
    float* __restrict__ out)            // (L, NBATCH, NSTATE)
{
    const int lane = threadIdx.x;   // 0..63
    const int col  = lane & 15;     // A-frag: row i (mod 16); B/D-frag: batch column
    const int quad = lane >> 4;     // 0..3
    const int b0   = blockIdx.x * 16;
    const int swz  = (col & 7) << 2;

    __shared__ unsigned int c_hi[1024];   // 2 buffers x 16 rows x 32 packed u32
    __shared__ unsigned int c_lo[1024];
    for (int i = lane; i < 1024; i += 64) { c_hi[i] = 0u; c_lo[i] = 0u; }

    // B-frag read offsets (uint4 per kk): logical u32 idx = 16*kk + 4*quad, XOR-swizzled by row
    const int rd0 = col * 32 + (( 0 + 4 * quad) ^ swz);
    const int rd1 = col * 32 + ((16 + 4 * quad) ^ swz);
    // c-write offsets per i-tile: logical u32 idx = 8*tile + 2*quad, XOR-swizzled by row
    int wr[4];
#pragma unroll
    for (int ts = 0; ts < 4; ++ts) wr[ts] = col * 32 + ((8 * ts + 2 * quad) ^ swz);

    // A-frag element offsets within one (64x64) matrix
    int aoff[4][2];
#pragma unroll
    for (int tl = 0; tl < 4; ++tl)
#pragma unroll
        for (int kk = 0; kk < 2; ++kk)
            aoff[tl][kk] = (16 * tl + col) * 64 + 32 * kk + 8 * quad;

    // Two prefetch register sets (named — never runtime-indexed)
    half8 ah0[4][2], al0[4][2], ah1[4][2], al1[4][2];
    float inp0, inp1;
    float4v bst0[4], bst1[4];

    auto load_set = [&](int t, half8 (&ah)[4][2], half8 (&al)[4][2],
                        float4v (&bstv)[4], float& inpv) {
#pragma unroll
        for (int tl = 0; tl < 4; ++tl) {
#pragma unroll
            for (int kk = 0; kk < 2; ++kk) {
                if constexpr (USE_WS) {
                    ah[tl][kk] = *(const half8*)(Ahi + (size_t)t * 4096 + aoff[tl][kk]);
                    al[tl][kk] = *(const half8*)(Alo + (size_t)t * 4096 + aoff[tl][kk]);
                } else {
                    const float* p = A32 + (size_t)t * 4096 + aoff[tl][kk];
                    float4v f0 = *(const float4v*)(p);
                    float4v f1 = *(const float4v*)(p + 4);
                    half8 h, l;
#pragma unroll
                    for (int e = 0; e < 4; ++e) {
                        float v0 = f0[e], v1 = f1[e];
                        _Float16 h0 = (_Float16)v0, h1 = (_Float16)v1;
                        h[e]     = h0;
                        h[e + 4] = h1;
                        l[e]     = (_Float16)(v0 - (float)h0);
                        l[e + 4] = (_Float16)(v1 - (float)h1);
                    }
                    ah[tl][kk] = h;
                    al[tl][kk] = l;
                }
            }
        }
        inpv = inp[t * NBATCH + b0 + col];
#pragma unroll
        for (int tl = 0; tl < 4; ++tl)
            bstv[tl] = *(const float4v*)(bst + t * NSTATE + 16 * tl + 4 * quad);
    };

    load_set(0, ah0, al0, bst0, inp0);
    load_set(1, ah1, al1, bst1, inp1);

    const float4v zero4 = {0.0f, 0.0f, 0.0f, 0.0f};

    auto step = [&](int t, int cur, half8 (&ah)[4][2], half8 (&al)[4][2],
                    float4v (&bstv)[4], float& inpv) {
        const int nxt = cur ^ 512;

        // B-operand: c^T, packed fp16 pairs -> half8 frags
        uint4v u_h0 = *(const uint4v*)(c_hi + cur + rd0);
        uint4v u_h1 = *(const uint4v*)(c_hi + cur + rd1);
        uint4v u_l0 = *(const uint4v*)(c_lo + cur + rd0);
        uint4v u_l1 = *(const uint4v*)(c_lo + cur + rd1);
        half8 ch[2] = { __builtin_bit_cast(half8, u_h0), __builtin_bit_cast(half8, u_h1) };
        half8 cl[2] = { __builtin_bit_cast(half8, u_l0), __builtin_bit_cast(half8, u_l1) };

        // 3-term split-precision product, fp32 accumulate.
        // Two partial accumulators per tile: chain depth 2 (A) + 4 (B) instead of 6.
        float4v acc[4];
#pragma unroll
        for (int tl = 0; tl < 4; ++tl) {
            float4v accA = bstv[tl] * inpv;
            accA = __builtin_amdgcn_mfma_f32_16x16x32_f16(ah[tl][0], ch[0], accA, 0, 0, 0);
            accA = __builtin_amdgcn_mfma_f32_16x16x32_f16(ah[tl][1], ch[1], accA, 0, 0, 0);
            float4v accB = __builtin_amdgcn_mfma_f32_16x16x32_f16(ah[tl][0], cl[0], zero4, 0, 0, 0);
            accB = __builtin_amdgcn_mfma_f32_16x16x32_f16(ah[tl][1], cl[1], accB, 0, 0, 0);
            accB = __builtin_amdgcn_mfma_f32_16x16x32_f16(al[tl][0], ch[0], accB, 0, 0, 0);
            accB = __builtin_amdgcn_mfma_f32_16x16x32_f16(al[tl][1], ch[1], accB, 0, 0, 0);
            acc[tl] = accA + accB;
        }

        // write c_t to global: lane has 4 consecutive i for its batch column
        float4v* outv = (float4v*)out;
#pragma unroll
        for (int tl = 0; tl < 4; ++tl)
            outv[(size_t)(t * NBATCH + b0 + col) * 16 + 4 * tl + quad] = acc[tl];

        // prefetch step t+2 into the SAME set (anti-dep keeps loads after the MFMAs)
        int tp = t + 2; if (tp > L_SEQ - 1) tp = L_SEQ - 1;
        load_set(tp, ah, al, bstv, inpv);

        // split c into fp16 hi/lo (RTZ hi + exact residual), pack, write other LDS buffer
#pragma unroll
        for (int tl = 0; tl < 4; ++tl) {
            fp16v2 h01 = __builtin_amdgcn_cvt_pkrtz(acc[tl].x, acc[tl].y);
            fp16v2 h23 = __builtin_amdgcn_cvt_pkrtz(acc[tl].z, acc[tl].w);
            fp16v2 l01 = __builtin_amdgcn_cvt_pkrtz(acc[tl].x - (float)h01.x, acc[tl].y - (float)h01.y);
            fp16v2 l23 = __builtin_amdgcn_cvt_pkrtz(acc[tl].z - (float)h23.x, acc[tl].w - (float)h23.y);
            uint2v hp = { __builtin_bit_cast(unsigned int, h01), __builtin_bit_cast(unsigned int, h23) };
            uint2v lp = { __builtin_bit_cast(unsigned int, l01), __builtin_bit_cast(unsigned int, l23) };
            *(uint2v*)(c_hi + nxt + wr[tl]) = hp;
            *(uint2v*)(c_lo + nxt + wr[tl]) = lp;
        }
    };

    for (int t = 0; t < L_SEQ; t += 2) {
        step(t,     0,   ah0, al0, bst0, inp0);
        step(t + 1, 512, ah1, al1, bst1, inp1);
    }
}

extern "C" void kernel_launch(void* const* d_in, const int* in_sizes, int n_in,
                              void* d_out, int out_size, void* d_ws, size_t ws_size,
                              hipStream_t stream) {
    const float* inputs = (const float*)d_in[0];
    const float* A_st   = (const float*)d_in[1];
    const float* B_st   = (const float*)d_in[2];
    float* out = (float*)d_out;

    const size_t n_a  = (size_t)L_SEQ * NSTATE * NSTATE;     // 4,194,304
    const size_t need = n_a * 2 * sizeof(_Float16);          // 16 MiB

    if (ws_size >= need) {
        _Float16* Ahi = (_Float16*)d_ws;
        _Float16* Alo = Ahi + n_a;
        split_A_kernel<<<(int)(n_a / 256), 256, 0, stream>>>(A_st, Ahi, Alo);
        hippo_scan_kernel<true><<<NBATCH / 16, 64, 0, stream>>>(inputs, B_st, A_st, Ahi, Alo, out);
    } else {
        hippo_scan_kernel<false><<<NBATCH / 16, 64, 0, stream>>>(inputs, B_st, A_st, nullptr, nullptr, out);
    }
}

// Round 4
// 932.242 us; speedup vs baseline: 1.2747x; 1.0837x over previous
//
#include <hip/hip_runtime.h>
#include <hip/hip_fp16.h>

#define L_SEQ  1024
#define NBATCH 2048
#define NSTATE 64
#define TCHK   64
#define NCHK   16    // L_SEQ / TCHK
#define KDIM   128   // NSTATE + TCHK

typedef _Float16 half8  __attribute__((ext_vector_type(8)));
typedef _Float16 half2s __attribute__((ext_vector_type(2)));
typedef float    float4v __attribute__((ext_vector_type(4)));
typedef unsigned int uint2v __attribute__((ext_vector_type(2)));
typedef unsigned int uint4v __attribute__((ext_vector_type(4)));

// ---------------------------------------------------------------------------
// Split A_stacked (f32) into fp16 hi + lo so that hi+lo ~ 22-bit mantissa.
__global__ __launch_bounds__(256) void split_A_kernel(const float* __restrict__ A,
                                                      _Float16* __restrict__ hi,
                                                      _Float16* __restrict__ lo) {
    int i = blockIdx.x * 256 + threadIdx.x;
    float a = A[i];
    _Float16 h = (_Float16)a;
    hi[i] = h;
    lo[i] = (_Float16)(a - (float)h);
}

// ---------------------------------------------------------------------------
// Kernel 1: build G_k for each chunk k (one block = one chunk, one wave).
// U (64 x 128) fp16 hi/lo packed in LDS (rows = output col c, 32 u32 r-pairs,
// XOR-swizzled) — exactly R3's verified exchange pattern, 8 col-tiles.
// Recurrence: U_i = A_t * U_{i-1}; inject B_t into column 64+i; store U_i as
// G row-block i (row-major (m=i*64+r, c), separate hi/lo fp16 arrays).
__global__ __launch_bounds__(64, 1) void build_G_kernel(
    const _Float16* __restrict__ Ahi,   // (L, 64, 64)
    const _Float16* __restrict__ Alo,
    const float* __restrict__ bst,      // (L, 64)
    _Float16* __restrict__ Ghi,         // (NCHK, 64*64, 128) row-major, pre-zeroed
    _Float16* __restrict__ Glo)
{
    const int lane = threadIdx.x;
    const int col  = lane & 15;
    const int quad = lane >> 4;
    const int chunk = blockIdx.x;
    const int swz  = (col & 7) << 2;

    __shared__ unsigned int u_hi[8192];   // 2 buf x 128 rows x 32 u32
    __shared__ unsigned int u_lo[8192];
    for (int i = lane; i < 8192; i += 64) { u_hi[i] = 0u; u_lo[i] = 0u; }
    // identity into buf0 (U_{-1} = [I | 0]); row c = lane, fp16 1.0 at r = c
    {
        int c = lane;
        u_hi[c * 32 + ((c >> 1) ^ ((c & 7) << 2))] = (c & 1) ? 0x3C000000u : 0x00003C00u;
    }

    int aoff[4][2];
#pragma unroll
    for (int tl = 0; tl < 4; ++tl)
#pragma unroll
        for (int kk = 0; kk < 2; ++kk)
            aoff[tl][kk] = (16 * tl + col) * 64 + 32 * kk + 8 * quad;

    half8 aH0[4][2], aL0[4][2], aH1[4][2], aL1[4][2];
    float4v bs0[4], bs1[4];

    auto loadA = [&](int i, half8 (&aH)[4][2], half8 (&aL)[4][2], float4v (&bs)[4]) {
        size_t base = (size_t)(chunk * TCHK + i) * 4096;
#pragma unroll
        for (int tl = 0; tl < 4; ++tl) {
#pragma unroll
            for (int kk = 0; kk < 2; ++kk) {
                aH[tl][kk] = *(const half8*)(Ahi + base + aoff[tl][kk]);
                aL[tl][kk] = *(const half8*)(Alo + base + aoff[tl][kk]);
            }
            bs[tl] = *(const float4v*)(bst + (chunk * TCHK + i) * NSTATE + 16 * tl + 4 * quad);
        }
    };

    loadA(0, aH0, aL0, bs0);
    loadA(1, aH1, aL1, bs1);

    const float4v zero4 = {0.0f, 0.0f, 0.0f, 0.0f};

    auto stepG = [&](int i, half8 (&aH)[4][2], half8 (&aL)[4][2], float4v (&bs)[4]) {
        const int cur = (i & 1) << 12;       // *4096
        const int nxt = cur ^ 4096;
        const int lim = 64 + i;              // highest active column
        const int inj_ct = lim >> 4, inj_c = lim & 15;

#pragma unroll
        for (int ct = 0; ct < 8; ++ct) {
            if (ct * 16 <= lim) {
                int rowb = cur + (ct * 16 + col) * 32;
                uint4v uh0 = *(const uint4v*)(u_hi + rowb + (( 0 + 4 * quad) ^ swz));
                uint4v uh1 = *(const uint4v*)(u_hi + rowb + ((16 + 4 * quad) ^ swz));
                uint4v ul0 = *(const uint4v*)(u_lo + rowb + (( 0 + 4 * quad) ^ swz));
                uint4v ul1 = *(const uint4v*)(u_lo + rowb + ((16 + 4 * quad) ^ swz));
                half8 ch0 = __builtin_bit_cast(half8, uh0), ch1 = __builtin_bit_cast(half8, uh1);
                half8 cl0 = __builtin_bit_cast(half8, ul0), cl1 = __builtin_bit_cast(half8, ul1);

#pragma unroll
                for (int tl = 0; tl < 4; ++tl) {
                    float4v a = zero4;
                    a = __builtin_amdgcn_mfma_f32_16x16x32_f16(aH[tl][0], ch0, a, 0, 0, 0);
                    a = __builtin_amdgcn_mfma_f32_16x16x32_f16(aH[tl][1], ch1, a, 0, 0, 0);
                    a = __builtin_amdgcn_mfma_f32_16x16x32_f16(aH[tl][0], cl0, a, 0, 0, 0);
                    a = __builtin_amdgcn_mfma_f32_16x16x32_f16(aH[tl][1], cl1, a, 0, 0, 0);
                    a = __builtin_amdgcn_mfma_f32_16x16x32_f16(aL[tl][0], ch0, a, 0, 0, 0);
                    a = __builtin_amdgcn_mfma_f32_16x16x32_f16(aL[tl][1], ch1, a, 0, 0, 0);
                    if (ct == inj_ct && col == inj_c) a += bs[tl];

                    _Float16 hx = (_Float16)a.x, hy = (_Float16)a.y;
                    _Float16 hz = (_Float16)a.z, hw = (_Float16)a.w;
                    _Float16 lx = (_Float16)(a.x - (float)hx), ly = (_Float16)(a.y - (float)hy);
                    _Float16 lz = (_Float16)(a.z - (float)hz), lw = (_Float16)(a.w - (float)hw);
                    half2s hp01; hp01.x = hx; hp01.y = hy;
                    half2s hp23; hp23.x = hz; hp23.y = hw;
                    half2s lp01; lp01.x = lx; lp01.y = ly;
                    half2s lp23; lp23.x = lz; lp23.y = lw;
                    uint2v hp = { __builtin_bit_cast(unsigned int, hp01), __builtin_bit_cast(unsigned int, hp23) };
                    uint2v lp = { __builtin_bit_cast(unsigned int, lp01), __builtin_bit_cast(unsigned int, lp23) };
                    *(uint2v*)(u_hi + nxt + (ct * 16 + col) * 32 + ((8 * tl + 2 * quad) ^ swz)) = hp;
                    *(uint2v*)(u_lo + nxt + (ct * 16 + col) * 32 + ((8 * tl + 2 * quad) ^ swz)) = lp;

                    size_t grow = ((size_t)(chunk * TCHK + i) * NSTATE + 16 * tl + 4 * quad) * KDIM + ct * 16 + col;
                    Ghi[grow          ] = hx; Glo[grow          ] = lx;
                    Ghi[grow +     KDIM] = hy; Glo[grow +     KDIM] = ly;
                    Ghi[grow + 2 * KDIM] = hz; Glo[grow + 2 * KDIM] = lz;
                    Ghi[grow + 3 * KDIM] = hw; Glo[grow + 3 * KDIM] = lw;
                }
            }
        }
        int tp = i + 2; if (tp > TCHK - 1) tp = TCHK - 1;
        loadA(tp, aH, aL, bs);
    };

    for (int i = 0; i < TCHK; i += 2) {
        stepG(i,     aH0, aL0, bs0);
        stepG(i + 1, aH1, aL1, bs1);
    }
}

// ---------------------------------------------------------------------------
// Kernel 2: boundary scan — s_{k+1} = G_k[last rowblock] @ [s_k; f_k].
// 128 blocks x 1 wave; each owns 16 batch columns; 16 serial chunk-steps.
// Stores s_k (packed fp16 hi/lo pairs, layout (k, b, 32 u32)) for kernel 3.
__global__ __launch_bounds__(64, 1) void boundary_kernel(
    const float* __restrict__ inp,      // (L, NBATCH)
    const _Float16* __restrict__ Ghi,
    const _Float16* __restrict__ Glo,
    unsigned int* __restrict__ s_hi,    // (NCHK, NBATCH, 32)
    unsigned int* __restrict__ s_lo)
{
    const int lane = threadIdx.x;
    const int col  = lane & 15;
    const int quad = lane >> 4;
    const int b0   = blockIdx.x * 16;
    const int swz  = (col & 7) << 2;

    __shared__ unsigned int c_hi[512];   // 16 rows(b) x 32 u32 (r-pairs)
    __shared__ unsigned int c_lo[512];
    for (int i = lane; i < 512; i += 64) { c_hi[i] = 0u; c_lo[i] = 0u; }

    // s_0 = 0
    {
        const uint4v z4 = {0u, 0u, 0u, 0u};
        size_t sb = ((size_t)b0 + col) * 32 + 8 * quad;
        *(uint4v*)(s_hi + sb) = z4; *(uint4v*)(s_hi + sb + 4) = z4;
        *(uint4v*)(s_lo + sb) = z4; *(uint4v*)(s_lo + sb + 4) = z4;
    }

    const float4v zero4 = {0.0f, 0.0f, 0.0f, 0.0f};

    for (int k = 0; k < NCHK; ++k) {
        // A-operand: last row-block (i = 63) of G_k
        half8 gh[4][4], gl[4][4];
#pragma unroll
        for (int tl = 0; tl < 4; ++tl)
#pragma unroll
            for (int kk = 0; kk < 4; ++kk) {
                size_t go = ((size_t)(k * TCHK + 63) * NSTATE + 16 * tl + col) * KDIM + 32 * kk + 8 * quad;
                gh[tl][kk] = *(const half8*)(Ghi + go);
                gl[tl][kk] = *(const half8*)(Glo + go);
            }

        // X: state part from LDS (kk 0,1)
        uint4v uh0 = *(const uint4v*)(c_hi + col * 32 + (( 0 + 4 * quad) ^ swz));
        uint4v uh1 = *(const uint4v*)(c_hi + col * 32 + ((16 + 4 * quad) ^ swz));
        uint4v ul0 = *(const uint4v*)(c_lo + col * 32 + (( 0 + 4 * quad) ^ swz));
        uint4v ul1 = *(const uint4v*)(c_lo + col * 32 + ((16 + 4 * quad) ^ swz));
        half8 xh[4], xl[4];
        xh[0] = __builtin_bit_cast(half8, uh0); xh[1] = __builtin_bit_cast(half8, uh1);
        xl[0] = __builtin_bit_cast(half8, ul0); xl[1] = __builtin_bit_cast(half8, ul1);
        // X: input part (kk 2,3) from global f, split hi/lo
#pragma unroll
        for (int kk2 = 0; kk2 < 2; ++kk2) {
            half8 h, l;
#pragma unroll
            for (int e = 0; e < 8; ++e) {
                float v = inp[(size_t)(k * TCHK + kk2 * 32 + 8 * quad + e) * NBATCH + b0 + col];
                _Float16 hh = (_Float16)v;
                h[e] = hh; l[e] = (_Float16)(v - (float)hh);
            }
            xh[2 + kk2] = h; xl[2 + kk2] = l;
        }

        float4v acc[4];
#pragma unroll
        for (int tl = 0; tl < 4; ++tl) {
            float4v a = zero4;
#pragma unroll
            for (int kk = 0; kk < 4; ++kk) {
                a = __builtin_amdgcn_mfma_f32_16x16x32_f16(gh[tl][kk], xh[kk], a, 0, 0, 0);
                a = __builtin_amdgcn_mfma_f32_16x16x32_f16(gh[tl][kk], xl[kk], a, 0, 0, 0);
                a = __builtin_amdgcn_mfma_f32_16x16x32_f16(gl[tl][kk], xh[kk], a, 0, 0, 0);
            }
            acc[tl] = a;
        }

        if (k < NCHK - 1) {
#pragma unroll
            for (int tl = 0; tl < 4; ++tl) {
                float4v a = acc[tl];
                _Float16 hx = (_Float16)a.x, hy = (_Float16)a.y;
                _Float16 hz = (_Float16)a.z, hw = (_Float16)a.w;
                _Float16 lx = (_Float16)(a.x - (float)hx), ly = (_Float16)(a.y - (float)hy);
                _Float16 lz = (_Float16)(a.z - (float)hz), lw = (_Float16)(a.w - (float)hw);
                half2s hp01; hp01.x = hx; hp01.y = hy;
                half2s hp23; hp23.x = hz; hp23.y = hw;
                half2s lp01; lp01.x = lx; lp01.y = ly;
                half2s lp23; lp23.x = lz; lp23.y = lw;
                uint2v hp = { __builtin_bit_cast(unsigned int, hp01), __builtin_bit_cast(unsigned int, hp23) };
                uint2v lp = { __builtin_bit_cast(unsigned int, lp01), __builtin_bit_cast(unsigned int, lp23) };
                *(uint2v*)(c_hi + col * 32 + ((8 * tl + 2 * quad) ^ swz)) = hp;
                *(uint2v*)(c_lo + col * 32 + ((8 * tl + 2 * quad) ^ swz)) = lp;
                size_t sb = ((size_t)(k + 1) * NBATCH + b0 + col) * 32 + 8 * tl + 2 * quad;
                *(uint2v*)(s_hi + sb) = hp;
                *(uint2v*)(s_lo + sb) = lp;
            }
        }
    }
}

// ---------------------------------------------------------------------------
// Kernel 3: apply — out[kT+i, b, :] = G_k[rowblock i] @ [s_k; f_k].
// Fully parallel GEMM: grid = chunk x i x btile, 4 waves x 16 batch cols.
__global__ __launch_bounds__(256) void apply_kernel(
    const float* __restrict__ inp,
    const _Float16* __restrict__ Ghi,
    const _Float16* __restrict__ Glo,
    const unsigned int* __restrict__ s_hi,
    const unsigned int* __restrict__ s_lo,
    float* __restrict__ out)
{
    const int tid  = threadIdx.x;
    const int lane = tid & 63;
    const int wave = tid >> 6;
    const int col  = lane & 15;
    const int quad = lane >> 4;
    const int bid   = blockIdx.x;
    const int btile = bid & 31;
    const int rest  = bid >> 5;
    const int i     = rest & 63;
    const int chunk = rest >> 6;
    const int b     = btile * 64 + wave * 16 + col;

    // X frags: state part
    size_t sb = ((size_t)chunk * NBATCH + b) * 32;
    uint4v sh0 = *(const uint4v*)(s_hi + sb +  0 + 4 * quad);
    uint4v sh1 = *(const uint4v*)(s_hi + sb + 16 + 4 * quad);
    uint4v sl0 = *(const uint4v*)(s_lo + sb +  0 + 4 * quad);
    uint4v sl1 = *(const uint4v*)(s_lo + sb + 16 + 4 * quad);
    half8 xh[4], xl[4];
    xh[0] = __builtin_bit_cast(half8, sh0); xh[1] = __builtin_bit_cast(half8, sh1);
    xl[0] = __builtin_bit_cast(half8, sl0); xl[1] = __builtin_bit_cast(half8, sl1);
    // X frags: input part
#pragma unroll
    for (int kk2 = 0; kk2 < 2; ++kk2) {
        half8 h, l;
#pragma unroll
        for (int e = 0; e < 8; ++e) {
            float v = inp[(size_t)(chunk * TCHK + kk2 * 32 + 8 * quad + e) * NBATCH + b];
            _Float16 hh = (_Float16)v;
            h[e] = hh; l[e] = (_Float16)(v - (float)hh);
        }
        xh[2 + kk2] = h; xl[2 + kk2] = l;
    }

    const float4v zero4 = {0.0f, 0.0f, 0.0f, 0.0f};
    float4v acc0 = zero4, acc1 = zero4, acc2 = zero4, acc3 = zero4;
    size_t grb = (size_t)(chunk * TCHK + i) * NSTATE;
#pragma unroll
    for (int kk = 0; kk < 4; ++kk) {
        size_t go0 = (grb + 16 * 0 + col) * KDIM + 32 * kk + 8 * quad;
        size_t go1 = (grb + 16 * 1 + col) * KDIM + 32 * kk + 8 * quad;
        size_t go2 = (grb + 16 * 2 + col) * KDIM + 32 * kk + 8 * quad;
        size_t go3 = (grb + 16 * 3 + col) * KDIM + 32 * kk + 8 * quad;
        half8 g0h = *(const half8*)(Ghi + go0), g0l = *(const half8*)(Glo + go0);
        half8 g1h = *(const half8*)(Ghi + go1), g1l = *(const half8*)(Glo + go1);
        half8 g2h = *(const half8*)(Ghi + go2), g2l = *(const half8*)(Glo + go2);
        half8 g3h = *(const half8*)(Ghi + go3), g3l = *(const half8*)(Glo + go3);
        acc0 = __builtin_amdgcn_mfma_f32_16x16x32_f16(g0h, xh[kk], acc0, 0, 0, 0);
        acc0 = __builtin_amdgcn_mfma_f32_16x16x32_f16(g0h, xl[kk], acc0, 0, 0, 0);
        acc0 = __builtin_amdgcn_mfma_f32_16x16x32_f16(g0l, xh[kk], acc0, 0, 0, 0);
        acc1 = __builtin_amdgcn_mfma_f32_16x16x32_f16(g1h, xh[kk], acc1, 0, 0, 0);
        acc1 = __builtin_amdgcn_mfma_f32_16x16x32_f16(g1h, xl[kk], acc1, 0, 0, 0);
        acc1 = __builtin_amdgcn_mfma_f32_16x16x32_f16(g1l, xh[kk], acc1, 0, 0, 0);
        acc2 = __builtin_amdgcn_mfma_f32_16x16x32_f16(g2h, xh[kk], acc2, 0, 0, 0);
        acc2 = __builtin_amdgcn_mfma_f32_16x16x32_f16(g2h, xl[kk], acc2, 0, 0, 0);
        acc2 = __builtin_amdgcn_mfma_f32_16x16x32_f16(g2l, xh[kk], acc2, 0, 0, 0);
        acc3 = __builtin_amdgcn_mfma_f32_16x16x32_f16(g3h, xh[kk], acc3, 0, 0, 0);
        acc3 = __builtin_amdgcn_mfma_f32_16x16x32_f16(g3h, xl[kk], acc3, 0, 0, 0);
        acc3 = __builtin_amdgcn_mfma_f32_16x16x32_f16(g3l, xh[kk], acc3, 0, 0, 0);
    }

    float4v* outv = (float4v*)out;
    size_t ob = ((size_t)(chunk * TCHK + i) * NBATCH + b) * 16;
    outv[ob + 4 * 0 + quad] = acc0;
    outv[ob + 4 * 1 + quad] = acc1;
    outv[ob + 4 * 2 + quad] = acc2;
    outv[ob + 4 * 3 + quad] = acc3;
}

// ---------------------------------------------------------------------------
// R3 fallback: sequential per-step scan (verified passing, 1010 us).
template <bool USE_WS>
__global__ __launch_bounds__(64, 1) void hippo_scan_kernel(
    const float* __restrict__ inp, const float* __restrict__ bst,
    const float* __restrict__ A32, const _Float16* __restrict__ Ahi,
    const _Float16* __restrict__ Alo, float* __restrict__ out)
{
    const int lane = threadIdx.x;
    const int col  = lane & 15;
    const int quad = lane >> 4;
    const int b0   = blockIdx.x * 16;
    const int swz  = (col & 7) << 2;

    __shared__ unsigned int c_hi[1024];
    __shared__ unsigned int c_lo[1024];
    for (int i = lane; i < 1024; i += 64) { c_hi[i] = 0u; c_lo[i] = 0u; }

    const int rd0 = col * 32 + (( 0 + 4 * quad) ^ swz);
    const int rd1 = col * 32 + ((16 + 4 * quad) ^ swz);
    int wr[4];
#pragma unroll
    for (int ts = 0; ts < 4; ++ts) wr[ts] = col * 32 + ((8 * ts + 2 * quad) ^ swz);

    int aoff[4][2];
#pragma unroll
    for (int tl = 0; tl < 4; ++tl)
#pragma unroll
        for (int kk = 0; kk < 2; ++kk)
            aoff[tl][kk] = (16 * tl + col) * 64 + 32 * kk + 8 * quad;

    half8 ah0[4][2], al0[4][2], ah1[4][2], al1[4][2];
    float inp0, inp1;
    float4v bst0[4], bst1[4];

    auto load_set = [&](int t, half8 (&ah)[4][2], half8 (&al)[4][2],
                        float4v (&bstv)[4], float& inpv) {
#pragma unroll
        for (int tl = 0; tl < 4; ++tl) {
#pragma unroll
            for (int kk = 0; kk < 2; ++kk) {
                if constexpr (USE_WS) {
                    ah[tl][kk] = *(const half8*)(Ahi + (size_t)t * 4096 + aoff[tl][kk]);
                    al[tl][kk] = *(const half8*)(Alo + (size_t)t * 4096 + aoff[tl][kk]);
                } else {
                    const float* p = A32 + (size_t)t * 4096 + aoff[tl][kk];
                    float4v f0 = *(const float4v*)(p);
                    float4v f1 = *(const float4v*)(p + 4);
                    half8 h, l;
#pragma unroll
                    for (int e = 0; e < 4; ++e) {
                        float v0 = f0[e], v1 = f1[e];
                        _Float16 h0 = (_Float16)v0, h1 = (_Float16)v1;
                        h[e] = h0; h[e + 4] = h1;
                        l[e] = (_Float16)(v0 - (float)h0);
                        l[e + 4] = (_Float16)(v1 - (float)h1);
                    }
                    ah[tl][kk] = h; al[tl][kk] = l;
                }
            }
        }
        inpv = inp[t * NBATCH + b0 + col];
#pragma unroll
        for (int tl = 0; tl < 4; ++tl)
            bstv[tl] = *(const float4v*)(bst + t * NSTATE + 16 * tl + 4 * quad);
    };

    load_set(0, ah0, al0, bst0, inp0);
    load_set(1, ah1, al1, bst1, inp1);
    const float4v zero4 = {0.0f, 0.0f, 0.0f, 0.0f};

    auto step = [&](int t, int cur, half8 (&ah)[4][2], half8 (&al)[4][2],
                    float4v (&bstv)[4], float& inpv) {
        const int nxt = cur ^ 512;
        uint4v u_h0 = *(const uint4v*)(c_hi + cur + rd0);
        uint4v u_h1 = *(const uint4v*)(c_hi + cur + rd1);
        uint4v u_l0 = *(const uint4v*)(c_lo + cur + rd0);
        uint4v u_l1 = *(const uint4v*)(c_lo + cur + rd1);
        half8 ch[2] = { __builtin_bit_cast(half8, u_h0), __builtin_bit_cast(half8, u_h1) };
        half8 cl[2] = { __builtin_bit_cast(half8, u_l0), __builtin_bit_cast(half8, u_l1) };

        float4v acc[4];
#pragma unroll
        for (int tl = 0; tl < 4; ++tl) {
            float4v accA = bstv[tl] * inpv;
            accA = __builtin_amdgcn_mfma_f32_16x16x32_f16(ah[tl][0], ch[0], accA, 0, 0, 0);
            accA = __builtin_amdgcn_mfma_f32_16x16x32_f16(ah[tl][1], ch[1], accA, 0, 0, 0);
            float4v accB = __builtin_amdgcn_mfma_f32_16x16x32_f16(ah[tl][0], cl[0], zero4, 0, 0, 0);
            accB = __builtin_amdgcn_mfma_f32_16x16x32_f16(ah[tl][1], cl[1], accB, 0, 0, 0);
            accB = __builtin_amdgcn_mfma_f32_16x16x32_f16(al[tl][0], ch[0], accB, 0, 0, 0);
            accB = __builtin_amdgcn_mfma_f32_16x16x32_f16(al[tl][1], ch[1], accB, 0, 0, 0);
            acc[tl] = accA + accB;
        }

        float4v* outv = (float4v*)out;
#pragma unroll
        for (int tl = 0; tl < 4; ++tl)
            outv[(size_t)(t * NBATCH + b0 + col) * 16 + 4 * tl + quad] = acc[tl];

        int tp = t + 2; if (tp > L_SEQ - 1) tp = L_SEQ - 1;
        load_set(tp, ah, al, bstv, inpv);

#pragma unroll
        for (int tl = 0; tl < 4; ++tl) {
            float x = acc[tl].x, y = acc[tl].y, z = acc[tl].z, w = acc[tl].w;
            _Float16 hx = (_Float16)x, hy = (_Float16)y, hz = (_Float16)z, hw = (_Float16)w;
            half2s hp01; hp01.x = hx; hp01.y = hy;
            half2s hp23; hp23.x = hz; hp23.y = hw;
            half2s lp01; lp01.x = (_Float16)(x - (float)hx); lp01.y = (_Float16)(y - (float)hy);
            half2s lp23; lp23.x = (_Float16)(z - (float)hz); lp23.y = (_Float16)(w - (float)hw);
            uint2v hp = { __builtin_bit_cast(unsigned int, hp01), __builtin_bit_cast(unsigned int, hp23) };
            uint2v lp = { __builtin_bit_cast(unsigned int, lp01), __builtin_bit_cast(unsigned int, lp23) };
            *(uint2v*)(c_hi + nxt + wr[tl]) = hp;
            *(uint2v*)(c_lo + nxt + wr[tl]) = lp;
        }
    };

    for (int t = 0; t < L_SEQ; t += 2) {
        step(t,     0,   ah0, al0, bst0, inp0);
        step(t + 1, 512, ah1, al1, bst1, inp1);
    }
}

// ---------------------------------------------------------------------------
extern "C" void kernel_launch(void* const* d_in, const int* in_sizes, int n_in,
                              void* d_out, int out_size, void* d_ws, size_t ws_size,
                              hipStream_t stream) {
    const float* inputs = (const float*)d_in[0];
    const float* A_st   = (const float*)d_in[1];
    const float* B_st   = (const float*)d_in[2];
    float* out = (float*)d_out;

    const size_t n_a    = (size_t)L_SEQ * NSTATE * NSTATE;                    // 4,194,304
    const size_t SZ_A   = n_a * sizeof(_Float16);                             // 8 MB
    const size_t SZ_G   = (size_t)NCHK * TCHK * NSTATE * KDIM * sizeof(_Float16); // 16 MB
    const size_t SZ_S   = (size_t)NCHK * NBATCH * 32 * sizeof(unsigned int);  // 4 MB
    const size_t OFF_ALO = SZ_A;
    const size_t OFF_GHI = 2 * SZ_A;
    const size_t OFF_GLO = OFF_GHI + SZ_G;
    const size_t OFF_SHI = OFF_GLO + SZ_G;
    const size_t OFF_SLO = OFF_SHI + SZ_S;
    const size_t NEED    = OFF_SLO + SZ_S;                                    // 56 MB

    if (ws_size >= NEED) {
        char* ws = (char*)d_ws;
        _Float16* Ahi = (_Float16*)ws;
        _Float16* Alo = (_Float16*)(ws + OFF_ALO);
        _Float16* Ghi = (_Float16*)(ws + OFF_GHI);
        _Float16* Glo = (_Float16*)(ws + OFF_GLO);
        unsigned int* shi = (unsigned int*)(ws + OFF_SHI);
        unsigned int* slo = (unsigned int*)(ws + OFF_SLO);

        split_A_kernel<<<(int)(n_a / 256), 256, 0, stream>>>(A_st, Ahi, Alo);
        hipMemsetAsync(ws + OFF_GHI, 0, 2 * SZ_G, stream);   // zero G tails
        build_G_kernel<<<NCHK, 64, 0, stream>>>(Ahi, Alo, B_st, Ghi, Glo);
        boundary_kernel<<<NBATCH / 16, 64, 0, stream>>>(inputs, Ghi, Glo, shi, slo);
        apply_kernel<<<NCHK * TCHK * 32, 256, 0, stream>>>(inputs, Ghi, Glo, shi, slo, out);
    } else if (ws_size >= 2 * SZ_A) {
        _Float16* Ahi = (_Float16*)d_ws;
        _Float16* Alo = Ahi + n_a;
        split_A_kernel<<<(int)(n_a / 256), 256, 0, stream>>>(A_st, Ahi, Alo);
        hippo_scan_kernel<true><<<NBATCH / 16, 64, 0, stream>>>(inputs, B_st, A_st, Ahi, Alo, out);
    } else {
        hippo_scan_kernel<false><<<NBATCH / 16, 64, 0, stream>>>(inputs, B_st, A_st, nullptr, nullptr, out);
    }
}

// Round 5
// 542.426 us; speedup vs baseline: 2.1908x; 1.7187x over previous
//
#include <hip/hip_runtime.h>
#include <hip/hip_fp16.h>

#define L_SEQ  1024
#define NBATCH 2048
#define NSTATE 64
#define TCHK   64
#define NCHK   16    // L_SEQ / TCHK
#define KDIM   128   // NSTATE + TCHK

typedef _Float16 half8  __attribute__((ext_vector_type(8)));
typedef _Float16 half2s __attribute__((ext_vector_type(2)));
typedef float    float4v __attribute__((ext_vector_type(4)));
typedef unsigned int uint2v __attribute__((ext_vector_type(2)));
typedef unsigned int uint4v __attribute__((ext_vector_type(4)));

// ---------------------------------------------------------------------------
__global__ __launch_bounds__(256) void split_A_kernel(const float* __restrict__ A,
                                                      _Float16* __restrict__ hi,
                                                      _Float16* __restrict__ lo) {
    int i = blockIdx.x * 256 + threadIdx.x;
    float a = A[i];
    _Float16 h = (_Float16)a;
    hi[i] = h;
    lo[i] = (_Float16)(a - (float)h);
}

// ---------------------------------------------------------------------------
// Kernel 1: build G_k per chunk (one block = one chunk, one wave). Unchanged (verified).
__global__ __launch_bounds__(64, 1) void build_G_kernel(
    const _Float16* __restrict__ Ahi,   // (L, 64, 64)
    const _Float16* __restrict__ Alo,
    const float* __restrict__ bst,      // (L, 64)
    _Float16* __restrict__ Ghi,         // (NCHK, 64*64, 128) row-major, pre-zeroed
    _Float16* __restrict__ Glo)
{
    const int lane = threadIdx.x;
    const int col  = lane & 15;
    const int quad = lane >> 4;
    const int chunk = blockIdx.x;
    const int swz  = (col & 7) << 2;

    __shared__ unsigned int u_hi[8192];   // 2 buf x 128 rows x 32 u32
    __shared__ unsigned int u_lo[8192];
    for (int i = lane; i < 8192; i += 64) { u_hi[i] = 0u; u_lo[i] = 0u; }
    {
        int c = lane;
        u_hi[c * 32 + ((c >> 1) ^ ((c & 7) << 2))] = (c & 1) ? 0x3C000000u : 0x00003C00u;
    }

    int aoff[4][2];
#pragma unroll
    for (int tl = 0; tl < 4; ++tl)
#pragma unroll
        for (int kk = 0; kk < 2; ++kk)
            aoff[tl][kk] = (16 * tl + col) * 64 + 32 * kk + 8 * quad;

    half8 aH0[4][2], aL0[4][2], aH1[4][2], aL1[4][2];
    float4v bs0[4], bs1[4];

    auto loadA = [&](int i, half8 (&aH)[4][2], half8 (&aL)[4][2], float4v (&bs)[4]) {
        size_t base = (size_t)(chunk * TCHK + i) * 4096;
#pragma unroll
        for (int tl = 0; tl < 4; ++tl) {
#pragma unroll
            for (int kk = 0; kk < 2; ++kk) {
                aH[tl][kk] = *(const half8*)(Ahi + base + aoff[tl][kk]);
                aL[tl][kk] = *(const half8*)(Alo + base + aoff[tl][kk]);
            }
            bs[tl] = *(const float4v*)(bst + (chunk * TCHK + i) * NSTATE + 16 * tl + 4 * quad);
        }
    };

    loadA(0, aH0, aL0, bs0);
    loadA(1, aH1, aL1, bs1);

    const float4v zero4 = {0.0f, 0.0f, 0.0f, 0.0f};

    auto stepG = [&](int i, half8 (&aH)[4][2], half8 (&aL)[4][2], float4v (&bs)[4]) {
        const int cur = (i & 1) << 12;
        const int nxt = cur ^ 4096;
        const int lim = 64 + i;
        const int inj_ct = lim >> 4, inj_c = lim & 15;

#pragma unroll
        for (int ct = 0; ct < 8; ++ct) {
            if (ct * 16 <= lim) {
                int rowb = cur + (ct * 16 + col) * 32;
                uint4v uh0 = *(const uint4v*)(u_hi + rowb + (( 0 + 4 * quad) ^ swz));
                uint4v uh1 = *(const uint4v*)(u_hi + rowb + ((16 + 4 * quad) ^ swz));
                uint4v ul0 = *(const uint4v*)(u_lo + rowb + (( 0 + 4 * quad) ^ swz));
                uint4v ul1 = *(const uint4v*)(u_lo + rowb + ((16 + 4 * quad) ^ swz));
                half8 ch0 = __builtin_bit_cast(half8, uh0), ch1 = __builtin_bit_cast(half8, uh1);
                half8 cl0 = __builtin_bit_cast(half8, ul0), cl1 = __builtin_bit_cast(half8, ul1);

#pragma unroll
                for (int tl = 0; tl < 4; ++tl) {
                    float4v a = zero4;
                    a = __builtin_amdgcn_mfma_f32_16x16x32_f16(aH[tl][0], ch0, a, 0, 0, 0);
                    a = __builtin_amdgcn_mfma_f32_16x16x32_f16(aH[tl][1], ch1, a, 0, 0, 0);
                    a = __builtin_amdgcn_mfma_f32_16x16x32_f16(aH[tl][0], cl0, a, 0, 0, 0);
                    a = __builtin_amdgcn_mfma_f32_16x16x32_f16(aH[tl][1], cl1, a, 0, 0, 0);
                    a = __builtin_amdgcn_mfma_f32_16x16x32_f16(aL[tl][0], ch0, a, 0, 0, 0);
                    a = __builtin_amdgcn_mfma_f32_16x16x32_f16(aL[tl][1], ch1, a, 0, 0, 0);
                    if (ct == inj_ct && col == inj_c) a += bs[tl];

                    _Float16 hx = (_Float16)a.x, hy = (_Float16)a.y;
                    _Float16 hz = (_Float16)a.z, hw = (_Float16)a.w;
                    _Float16 lx = (_Float16)(a.x - (float)hx), ly = (_Float16)(a.y - (float)hy);
                    _Float16 lz = (_Float16)(a.z - (float)hz), lw = (_Float16)(a.w - (float)hw);
                    half2s hp01; hp01.x = hx; hp01.y = hy;
                    half2s hp23; hp23.x = hz; hp23.y = hw;
                    half2s lp01; lp01.x = lx; lp01.y = ly;
                    half2s lp23; lp23.x = lz; lp23.y = lw;
                    uint2v hp = { __builtin_bit_cast(unsigned int, hp01), __builtin_bit_cast(unsigned int, hp23) };
                    uint2v lp = { __builtin_bit_cast(unsigned int, lp01), __builtin_bit_cast(unsigned int, lp23) };
                    *(uint2v*)(u_hi + nxt + (ct * 16 + col) * 32 + ((8 * tl + 2 * quad) ^ swz)) = hp;
                    *(uint2v*)(u_lo + nxt + (ct * 16 + col) * 32 + ((8 * tl + 2 * quad) ^ swz)) = lp;

                    size_t grow = ((size_t)(chunk * TCHK + i) * NSTATE + 16 * tl + 4 * quad) * KDIM + ct * 16 + col;
                    Ghi[grow          ] = hx; Glo[grow          ] = lx;
                    Ghi[grow +     KDIM] = hy; Glo[grow +     KDIM] = ly;
                    Ghi[grow + 2 * KDIM] = hz; Glo[grow + 2 * KDIM] = lz;
                    Ghi[grow + 3 * KDIM] = hw; Glo[grow + 3 * KDIM] = lw;
                }
            }
        }
        int tp = i + 2; if (tp > TCHK - 1) tp = TCHK - 1;
        loadA(tp, aH, aL, bs);
    };

    for (int i = 0; i < TCHK; i += 2) {
        stepG(i,     aH0, aL0, bs0);
        stepG(i + 1, aH1, aL1, bs1);
    }
}

// ---------------------------------------------------------------------------
// Kernel 2: boundary scan. Unchanged (verified).
__global__ __launch_bounds__(64, 1) void boundary_kernel(
    const float* __restrict__ inp,
    const _Float16* __restrict__ Ghi,
    const _Float16* __restrict__ Glo,
    unsigned int* __restrict__ s_hi,    // (NCHK, NBATCH, 32)
    unsigned int* __restrict__ s_lo)
{
    const int lane = threadIdx.x;
    const int col  = lane & 15;
    const int quad = lane >> 4;
    const int b0   = blockIdx.x * 16;
    const int swz  = (col & 7) << 2;

    __shared__ unsigned int c_hi[512];
    __shared__ unsigned int c_lo[512];
    for (int i = lane; i < 512; i += 64) { c_hi[i] = 0u; c_lo[i] = 0u; }

    {
        const uint4v z4 = {0u, 0u, 0u, 0u};
        size_t sb = ((size_t)b0 + col) * 32 + 8 * quad;
        *(uint4v*)(s_hi + sb) = z4; *(uint4v*)(s_hi + sb + 4) = z4;
        *(uint4v*)(s_lo + sb) = z4; *(uint4v*)(s_lo + sb + 4) = z4;
    }

    const float4v zero4 = {0.0f, 0.0f, 0.0f, 0.0f};

    for (int k = 0; k < NCHK; ++k) {
        half8 gh[4][4], gl[4][4];
#pragma unroll
        for (int tl = 0; tl < 4; ++tl)
#pragma unroll
            for (int kk = 0; kk < 4; ++kk) {
                size_t go = ((size_t)(k * TCHK + 63) * NSTATE + 16 * tl + col) * KDIM + 32 * kk + 8 * quad;
                gh[tl][kk] = *(const half8*)(Ghi + go);
                gl[tl][kk] = *(const half8*)(Glo + go);
            }

        uint4v uh0 = *(const uint4v*)(c_hi + col * 32 + (( 0 + 4 * quad) ^ swz));
        uint4v uh1 = *(const uint4v*)(c_hi + col * 32 + ((16 + 4 * quad) ^ swz));
        uint4v ul0 = *(const uint4v*)(c_lo + col * 32 + (( 0 + 4 * quad) ^ swz));
        uint4v ul1 = *(const uint4v*)(c_lo + col * 32 + ((16 + 4 * quad) ^ swz));
        half8 xh[4], xl[4];
        xh[0] = __builtin_bit_cast(half8, uh0); xh[1] = __builtin_bit_cast(half8, uh1);
        xl[0] = __builtin_bit_cast(half8, ul0); xl[1] = __builtin_bit_cast(half8, ul1);
#pragma unroll
        for (int kk2 = 0; kk2 < 2; ++kk2) {
            half8 h, l;
#pragma unroll
            for (int e = 0; e < 8; ++e) {
                float v = inp[(size_t)(k * TCHK + kk2 * 32 + 8 * quad + e) * NBATCH + b0 + col];
                _Float16 hh = (_Float16)v;
                h[e] = hh; l[e] = (_Float16)(v - (float)hh);
            }
            xh[2 + kk2] = h; xl[2 + kk2] = l;
        }

        float4v acc[4];
#pragma unroll
        for (int tl = 0; tl < 4; ++tl) {
            float4v a = zero4;
#pragma unroll
            for (int kk = 0; kk < 4; ++kk) {
                a = __builtin_amdgcn_mfma_f32_16x16x32_f16(gh[tl][kk], xh[kk], a, 0, 0, 0);
                a = __builtin_amdgcn_mfma_f32_16x16x32_f16(gh[tl][kk], xl[kk], a, 0, 0, 0);
                a = __builtin_amdgcn_mfma_f32_16x16x32_f16(gl[tl][kk], xh[kk], a, 0, 0, 0);
            }
            acc[tl] = a;
        }

        if (k < NCHK - 1) {
#pragma unroll
            for (int tl = 0; tl < 4; ++tl) {
                float4v a = acc[tl];
                _Float16 hx = (_Float16)a.x, hy = (_Float16)a.y;
                _Float16 hz = (_Float16)a.z, hw = (_Float16)a.w;
                _Float16 lx = (_Float16)(a.x - (float)hx), ly = (_Float16)(a.y - (float)hy);
                _Float16 lz = (_Float16)(a.z - (float)hz), lw = (_Float16)(a.w - (float)hw);
                half2s hp01; hp01.x = hx; hp01.y = hy;
                half2s hp23; hp23.x = hz; hp23.y = hw;
                half2s lp01; lp01.x = lx; lp01.y = ly;
                half2s lp23; lp23.x = lz; lp23.y = lw;
                uint2v hp = { __builtin_bit_cast(unsigned int, hp01), __builtin_bit_cast(unsigned int, hp23) };
                uint2v lp = { __builtin_bit_cast(unsigned int, lp01), __builtin_bit_cast(unsigned int, lp23) };
                *(uint2v*)(c_hi + col * 32 + ((8 * tl + 2 * quad) ^ swz)) = hp;
                *(uint2v*)(c_lo + col * 32 + ((8 * tl + 2 * quad) ^ swz)) = lp;
                size_t sb = ((size_t)(k + 1) * NBATCH + b0 + col) * 32 + 8 * tl + 2 * quad;
                *(uint2v*)(s_hi + sb) = hp;
                *(uint2v*)(s_lo + sb) = lp;
            }
        }
    }
}

// ---------------------------------------------------------------------------
// Kernel 3 v2: pipelined apply.
// Block = (chunk, igroup of 8, btile of 128 b). 4 waves x 32 b (2 bsets of 16).
// Per i: G row-block staged to double-buffered LDS in FRAGMENT layout (wave w
// stages tl=w via reg-loads with the verified v1 address formula, ds_write at
// lane*16 -> linear, conflict-free; reads are stride-1 ds_read_b128).
// Prefetch(i+1) issues before compute(i) -> full-iteration latency hiding.
// XCD-swizzled block ids: each XCD owns 2 chunks -> G working set 4MB = its L2.
__global__ __launch_bounds__(256, 1) void apply2_kernel(
    const float* __restrict__ inp,
    const _Float16* __restrict__ Ghi,
    const _Float16* __restrict__ Glo,
    const unsigned int* __restrict__ s_hi,
    const unsigned int* __restrict__ s_lo,
    float* __restrict__ out)
{
    const int tid  = threadIdx.x;
    const int lane = tid & 63;
    const int wave = tid >> 6;
    const int col  = lane & 15;
    const int quad = lane >> 4;

    // bijective XCD swizzle: 2048 blocks, 8 XCDs, 256 per XCD
    const int virt  = (blockIdx.x & 7) * 256 + (blockIdx.x >> 3);
    const int chunk = virt >> 7;          // 16
    const int ig    = (virt >> 4) & 7;    // 8
    const int bt    = virt & 15;          // 16 btiles of 128 b

    __shared__ _Float16 gbuf[2][2][16][64][8];  // [buf][hi/lo][tl*4+kk][lane][8] = 64 KiB

    // ---- X fragments for 2 bsets (b = bt*128 + wave*32 + bs*16 + col) ----
    int bb[2];
    bb[0] = bt * 128 + wave * 32 + col;
    bb[1] = bb[0] + 16;
    half8 xh[2][4], xl[2][4];
#pragma unroll
    for (int bs = 0; bs < 2; ++bs) {
        size_t sb = ((size_t)chunk * NBATCH + bb[bs]) * 32;
        uint4v sh0 = *(const uint4v*)(s_hi + sb +  0 + 4 * quad);
        uint4v sh1 = *(const uint4v*)(s_hi + sb + 16 + 4 * quad);
        uint4v sl0 = *(const uint4v*)(s_lo + sb +  0 + 4 * quad);
        uint4v sl1 = *(const uint4v*)(s_lo + sb + 16 + 4 * quad);
        xh[bs][0] = __builtin_bit_cast(half8, sh0); xh[bs][1] = __builtin_bit_cast(half8, sh1);
        xl[bs][0] = __builtin_bit_cast(half8, sl0); xl[bs][1] = __builtin_bit_cast(half8, sl1);
#pragma unroll
        for (int kk2 = 0; kk2 < 2; ++kk2) {
            half8 h, l;
#pragma unroll
            for (int e = 0; e < 8; ++e) {
                float v = inp[(size_t)(chunk * TCHK + kk2 * 32 + 8 * quad + e) * NBATCH + bb[bs]];
                _Float16 hh = (_Float16)v;
                h[e] = hh; l[e] = (_Float16)(v - (float)hh);
            }
            xh[bs][2 + kk2] = h; xl[bs][2 + kk2] = l;
        }
    }

    // ---- staging helpers (wave stages tl = wave) ----
    half8 sreg[8];   // [kk*2 + hi/lo], only compile-time indices after unroll
    auto stage_issue = [&](int i) {
        size_t base = ((size_t)(chunk * TCHK + ig * 8 + i) * NSTATE + 16 * wave + col) * KDIM + 8 * quad;
#pragma unroll
        for (int kk = 0; kk < 4; ++kk) {
            sreg[kk * 2 + 0] = *(const half8*)(Ghi + base + 32 * kk);
            sreg[kk * 2 + 1] = *(const half8*)(Glo + base + 32 * kk);
        }
    };
    auto stage_write = [&](int buf) {
#pragma unroll
        for (int kk = 0; kk < 4; ++kk) {
            *(half8*)&gbuf[buf][0][wave * 4 + kk][lane][0] = sreg[kk * 2 + 0];
            *(half8*)&gbuf[buf][1][wave * 4 + kk][lane][0] = sreg[kk * 2 + 1];
        }
    };

    const float4v zero4 = {0.0f, 0.0f, 0.0f, 0.0f};
    float4v* outv = (float4v*)out;

    // prologue
    stage_issue(0);
    stage_write(0);
    __syncthreads();

    for (int i = 0; i < 8; ++i) {
        const int cur = i & 1;
        if (i < 7) stage_issue(i + 1);      // async loads, land during compute

        float4v acc[2][4];
#pragma unroll
        for (int bs = 0; bs < 2; ++bs)
#pragma unroll
            for (int tl = 0; tl < 4; ++tl) acc[bs][tl] = zero4;

#pragma unroll
        for (int kk = 0; kk < 4; ++kk) {
            half8 gh[4], gl[4];
#pragma unroll
            for (int tl = 0; tl < 4; ++tl) {
                gh[tl] = *(const half8*)&gbuf[cur][0][tl * 4 + kk][lane][0];
                gl[tl] = *(const half8*)&gbuf[cur][1][tl * 4 + kk][lane][0];
            }
#pragma unroll
            for (int tl = 0; tl < 4; ++tl) {
#pragma unroll
                for (int bs = 0; bs < 2; ++bs) {
                    acc[bs][tl] = __builtin_amdgcn_mfma_f32_16x16x32_f16(gh[tl], xh[bs][kk], acc[bs][tl], 0, 0, 0);
                    acc[bs][tl] = __builtin_amdgcn_mfma_f32_16x16x32_f16(gh[tl], xl[bs][kk], acc[bs][tl], 0, 0, 0);
                    acc[bs][tl] = __builtin_amdgcn_mfma_f32_16x16x32_f16(gl[tl], xh[bs][kk], acc[bs][tl], 0, 0, 0);
                }
            }
        }

        const size_t tt = (size_t)(chunk * TCHK + ig * 8 + i);
#pragma unroll
        for (int bs = 0; bs < 2; ++bs)
#pragma unroll
            for (int tl = 0; tl < 4; ++tl)
                outv[(tt * NBATCH + bb[bs]) * 16 + 4 * tl + quad] = acc[bs][tl];

        if (i < 7) stage_write(cur ^ 1);    // waits the prefetch loads (had full compute to land)
        __syncthreads();
    }
}

// ---------------------------------------------------------------------------
// R3 fallback: sequential per-step scan (verified passing).
template <bool USE_WS>
__global__ __launch_bounds__(64, 1) void hippo_scan_kernel(
    const float* __restrict__ inp, const float* __restrict__ bst,
    const float* __restrict__ A32, const _Float16* __restrict__ Ahi,
    const _Float16* __restrict__ Alo, float* __restrict__ out)
{
    const int lane = threadIdx.x;
    const int col  = lane & 15;
    const int quad = lane >> 4;
    const int b0   = blockIdx.x * 16;
    const int swz  = (col & 7) << 2;

    __shared__ unsigned int c_hi[1024];
    __shared__ unsigned int c_lo[1024];
    for (int i = lane; i < 1024; i += 64) { c_hi[i] = 0u; c_lo[i] = 0u; }

    const int rd0 = col * 32 + (( 0 + 4 * quad) ^ swz);
    const int rd1 = col * 32 + ((16 + 4 * quad) ^ swz);
    int wr[4];
#pragma unroll
    for (int ts = 0; ts < 4; ++ts) wr[ts] = col * 32 + ((8 * ts + 2 * quad) ^ swz);

    int aoff[4][2];
#pragma unroll
    for (int tl = 0; tl < 4; ++tl)
#pragma unroll
        for (int kk = 0; kk < 2; ++kk)
            aoff[tl][kk] = (16 * tl + col) * 64 + 32 * kk + 8 * quad;

    half8 ah0[4][2], al0[4][2], ah1[4][2], al1[4][2];
    float inp0, inp1;
    float4v bst0[4], bst1[4];

    auto load_set = [&](int t, half8 (&ah)[4][2], half8 (&al)[4][2],
                        float4v (&bstv)[4], float& inpv) {
#pragma unroll
        for (int tl = 0; tl < 4; ++tl) {
#pragma unroll
            for (int kk = 0; kk < 2; ++kk) {
                if constexpr (USE_WS) {
                    ah[tl][kk] = *(const half8*)(Ahi + (size_t)t * 4096 + aoff[tl][kk]);
                    al[tl][kk] = *(const half8*)(Alo + (size_t)t * 4096 + aoff[tl][kk]);
                } else {
                    const float* p = A32 + (size_t)t * 4096 + aoff[tl][kk];
                    float4v f0 = *(const float4v*)(p);
                    float4v f1 = *(const float4v*)(p + 4);
                    half8 h, l;
#pragma unroll
                    for (int e = 0; e < 4; ++e) {
                        float v0 = f0[e], v1 = f1[e];
                        _Float16 h0 = (_Float16)v0, h1 = (_Float16)v1;
                        h[e] = h0; h[e + 4] = h1;
                        l[e] = (_Float16)(v0 - (float)h0);
                        l[e + 4] = (_Float16)(v1 - (float)h1);
                    }
                    ah[tl][kk] = h; al[tl][kk] = l;
                }
            }
        }
        inpv = inp[t * NBATCH + b0 + col];
#pragma unroll
        for (int tl = 0; tl < 4; ++tl)
            bstv[tl] = *(const float4v*)(bst + t * NSTATE + 16 * tl + 4 * quad);
    };

    load_set(0, ah0, al0, bst0, inp0);
    load_set(1, ah1, al1, bst1, inp1);
    const float4v zero4 = {0.0f, 0.0f, 0.0f, 0.0f};

    auto step = [&](int t, int cur, half8 (&ah)[4][2], half8 (&al)[4][2],
                    float4v (&bstv)[4], float& inpv) {
        const int nxt = cur ^ 512;
        uint4v u_h0 = *(const uint4v*)(c_hi + cur + rd0);
        uint4v u_h1 = *(const uint4v*)(c_hi + cur + rd1);
        uint4v u_l0 = *(const uint4v*)(c_lo + cur + rd0);
        uint4v u_l1 = *(const uint4v*)(c_lo + cur + rd1);
        half8 ch[2] = { __builtin_bit_cast(half8, u_h0), __builtin_bit_cast(half8, u_h1) };
        half8 cl[2] = { __builtin_bit_cast(half8, u_l0), __builtin_bit_cast(half8, u_l1) };

        float4v acc[4];
#pragma unroll
        for (int tl = 0; tl < 4; ++tl) {
            float4v accA = bstv[tl] * inpv;
            accA = __builtin_amdgcn_mfma_f32_16x16x32_f16(ah[tl][0], ch[0], accA, 0, 0, 0);
            accA = __builtin_amdgcn_mfma_f32_16x16x32_f16(ah[tl][1], ch[1], accA, 0, 0, 0);
            float4v accB = __builtin_amdgcn_mfma_f32_16x16x32_f16(ah[tl][0], cl[0], zero4, 0, 0, 0);
            accB = __builtin_amdgcn_mfma_f32_16x16x32_f16(ah[tl][1], cl[1], accB, 0, 0, 0);
            accB = __builtin_amdgcn_mfma_f32_16x16x32_f16(al[tl][0], ch[0], accB, 0, 0, 0);
            accB = __builtin_amdgcn_mfma_f32_16x16x32_f16(al[tl][1], ch[1], accB, 0, 0, 0);
            acc[tl] = accA + accB;
        }

        float4v* outv = (float4v*)out;
#pragma unroll
        for (int tl = 0; tl < 4; ++tl)
            outv[(size_t)(t * NBATCH + b0 + col) * 16 + 4 * tl + quad] = acc[tl];

        int tp = t + 2; if (tp > L_SEQ - 1) tp = L_SEQ - 1;
        load_set(tp, ah, al, bstv, inpv);

#pragma unroll
        for (int tl = 0; tl < 4; ++tl) {
            float x = acc[tl].x, y = acc[tl].y, z = acc[tl].z, w = acc[tl].w;
            _Float16 hx = (_Float16)x, hy = (_Float16)y, hz = (_Float16)z, hw = (_Float16)w;
            half2s hp01; hp01.x = hx; hp01.y = hy;
            half2s hp23; hp23.x = hz; hp23.y = hw;
            half2s lp01; lp01.x = (_Float16)(x - (float)hx); lp01.y = (_Float16)(y - (float)hy);
            half2s lp23; lp23.x = (_Float16)(z - (float)hz); lp23.y = (_Float16)(w - (float)hw);
            uint2v hp = { __builtin_bit_cast(unsigned int, hp01), __builtin_bit_cast(unsigned int, hp23) };
            uint2v lp = { __builtin_bit_cast(unsigned int, lp01), __builtin_bit_cast(unsigned int, lp23) };
            *(uint2v*)(c_hi + nxt + wr[tl]) = hp;
            *(uint2v*)(c_lo + nxt + wr[tl]) = lp;
        }
    };

    for (int t = 0; t < L_SEQ; t += 2) {
        step(t,     0,   ah0, al0, bst0, inp0);
        step(t + 1, 512, ah1, al1, bst1, inp1);
    }
}

// ---------------------------------------------------------------------------
extern "C" void kernel_launch(void* const* d_in, const int* in_sizes, int n_in,
                              void* d_out, int out_size, void* d_ws, size_t ws_size,
                              hipStream_t stream) {
    const float* inputs = (const float*)d_in[0];
    const float* A_st   = (const float*)d_in[1];
    const float* B_st   = (const float*)d_in[2];
    float* out = (float*)d_out;

    const size_t n_a    = (size_t)L_SEQ * NSTATE * NSTATE;
    const size_t SZ_A   = n_a * sizeof(_Float16);                                 // 8 MB
    const size_t SZ_G   = (size_t)NCHK * TCHK * NSTATE * KDIM * sizeof(_Float16); // 16 MB
    const size_t SZ_S   = (size_t)NCHK * NBATCH * 32 * sizeof(unsigned int);      // 4 MB
    const size_t OFF_ALO = SZ_A;
    const size_t OFF_GHI = 2 * SZ_A;
    const size_t OFF_GLO = OFF_GHI + SZ_G;
    const size_t OFF_SHI = OFF_GLO + SZ_G;
    const size_t OFF_SLO = OFF_SHI + SZ_S;
    const size_t NEED    = OFF_SLO + SZ_S;                                        // 56 MB

    if (ws_size >= NEED) {
        char* ws = (char*)d_ws;
        _Float16* Ahi = (_Float16*)ws;
        _Float16* Alo = (_Float16*)(ws + OFF_ALO);
        _Float16* Ghi = (_Float16*)(ws + OFF_GHI);
        _Float16* Glo = (_Float16*)(ws + OFF_GLO);
        unsigned int* shi = (unsigned int*)(ws + OFF_SHI);
        unsigned int* slo = (unsigned int*)(ws + OFF_SLO);

        split_A_kernel<<<(int)(n_a / 256), 256, 0, stream>>>(A_st, Ahi, Alo);
        hipMemsetAsync(ws + OFF_GHI, 0, 2 * SZ_G, stream);   // zero G tails
        build_G_kernel<<<NCHK, 64, 0, stream>>>(Ahi, Alo, B_st, Ghi, Glo);
        boundary_kernel<<<NBATCH / 16, 64, 0, stream>>>(inputs, Ghi, Glo, shi, slo);
        apply2_kernel<<<NCHK * 8 * 16, 256, 0, stream>>>(inputs, Ghi, Glo, shi, slo, out);
    } else if (ws_size >= 2 * SZ_A) {
        _Float16* Ahi = (_Float16*)d_ws;
        _Float16* Alo = Ahi + n_a;
        split_A_kernel<<<(int)(n_a / 256), 256, 0, stream>>>(A_st, Ahi, Alo);
        hippo_scan_kernel<true><<<NBATCH / 16, 64, 0, stream>>>(inputs, B_st, A_st, Ahi, Alo, out);
    } else {
        hippo_scan_kernel<false><<<NBATCH / 16, 64, 0, stream>>>(inputs, B_st, A_st, nullptr, nullptr, out);
    }
}